// Round 5
// baseline (102.999 us; speedup 1.0000x reference)
//
#include <hip/hip_runtime.h>
#include <hip/hip_fp16.h>
#include <math.h>

#define LMAX 10
#define NCOL 121                 // (LMAX+1)^2
#define PPB  64                  // points per tile
#define TILEH (PPB * NCOL)       // 7744 halves per buffer
#define TILE4 (PPB * NCOL / 4)   // 1936 output float4 per tile

typedef float f4_t __attribute__((ext_vector_type(4)));

struct Tab {
    float K[66];   // K(l,m) (* sqrt2 for m>0), index l(l+1)/2+m
    float A[66];   // (2l-1)/(l-m)    for l>=m+2
    float B[66];   // (l+m-1)/(l-m)   for l>=m+2
};

// ---- chain for fixed M: emit K*P(l,M)*rf^l * {cos,sin}(M phi), l=M..LMAX ----
template<int M, typename ST, typename EMIT>
__device__ __forceinline__ void chain(const Tab& t, ST* __restrict__ row,
                                      float pmm, float rfm, float rf, float x,
                                      float cm, float sm, EMIT emit) {
    {
        float v = t.K[M * (M + 1) / 2 + M] * pmm * rfm;
        if constexpr (M == 0) emit(row, 0, v);
        else { emit(row, M * M + 2 * M, v * cm); emit(row, M * M, v * sm); }
    }
    if constexpr (M < LMAX) {
        float p0 = pmm;
        float p1 = x * (float)(2 * M + 1) * pmm;
        float rfl = rfm * rf;
        {
            constexpr int L = M + 1;
            float v = t.K[L * (L + 1) / 2 + M] * p1 * rfl;
            if constexpr (M == 0) emit(row, L * L + L, v);
            else { emit(row, L * L + L + M, v * cm); emit(row, L * L + L - M, v * sm); }
        }
#pragma unroll
        for (int ll = M + 2; ll <= LMAX; ++ll) {
            int ti = ll * (ll + 1) / 2 + M;
            float p2 = t.A[ti] * x * p1 - t.B[ti] * p0;
            p0 = p1; p1 = p2;
            rfl *= rf;
            float v = t.K[ti] * p1 * rfl;
            int jb = ll * ll + ll;
            if constexpr (M == 0) emit(row, jb, v);
            else { emit(row, jb + M, v * cm); emit(row, jb - M, v * sm); }
        }
    }
}

// ---- compute one 64-point tile into an LDS buffer (element type ST) ----
template<typename ST, typename EMIT>
__device__ __forceinline__ void compute_tile(const float* __restrict__ in,
                                             long long gp, int s, const Tab& t,
                                             ST* __restrict__ row, EMIT emit) {
    const float lon = in[gp * 3 + 0];
    const float lat = in[gp * 3 + 1];
    const float r   = in[gp * 3 + 2];

    const float D2R  = 0.017453292519943295f;
    const float PI_F = 3.14159265358979323846f;

    float phi   = (lon + 180.0f) * D2R;
    float theta = fminf(fmaxf((90.0f - lat) * D2R, 1e-7f), PI_F - 1e-7f);
    float x = __cosf(theta);
    x = fminf(fmaxf(x, -1.0f + 1e-7f), 1.0f - 1e-7f);
    float somx2 = sqrtf(fmaxf((1.0f - x) * (1.0f + x), 0.0f));
    float rf  = 6371000.0f / r;
    float rf2 = rf * rf;
    float rf3 = rf2 * rf;
    float rf5 = rf3 * rf2;

    float c1, s1;
    __sincosf(phi, &s1, &c1);
    float c2 = c1 * c1 - s1 * s1, s2 = 2.0f * c1 * s1;
    float c3 = c2 * c1 - s2 * s1, s3 = s2 * c1 + c2 * s1;
    float c5 = (c2 * c2 - s2 * s2) * c1 - 2.0f * c2 * s2 * s1;
    float s5 = 2.0f * c2 * s2 * c1 + (c2 * c2 - s2 * s2) * s1;

    float sx2 = somx2 * somx2;
    float sx3 = sx2 * somx2;
    float sx5 = sx3 * sx2;

#define ROT(cm, sm, ck, sk) { float cn = cm * ck - sm * sk; sm = sm * ck + cm * sk; cm = cn; }
    // m-sets balanced by chain length: {0,5,10}, {1,6,9}, {2,7,8}, {3,4}
    switch (s) {
    case 0: {
        float pmm = 1.0f, rfm = 1.0f, cm = 1.0f, sm = 0.0f;
        chain<0>(t, row, pmm, rfm, rf, x, cm, sm, emit);
        pmm *= -945.0f    * sx5; rfm *= rf5; ROT(cm, sm, c5, s5);   // 1*3*5*7*9
        chain<5>(t, row, pmm, rfm, rf, x, cm, sm, emit);
        pmm *= -692835.0f * sx5; rfm *= rf5; ROT(cm, sm, c5, s5);   // 11*13*15*17*19
        chain<10>(t, row, pmm, rfm, rf, x, cm, sm, emit);
    } break;
    case 1: {
        float pmm = -somx2, rfm = rf, cm = c1, sm = s1;
        chain<1>(t, row, pmm, rfm, rf, x, cm, sm, emit);
        pmm *= -10395.0f * sx5; rfm *= rf5; ROT(cm, sm, c5, s5);    // 3*5*7*9*11
        chain<6>(t, row, pmm, rfm, rf, x, cm, sm, emit);
        pmm *= -3315.0f  * sx3; rfm *= rf3; ROT(cm, sm, c3, s3);    // 13*15*17
        chain<9>(t, row, pmm, rfm, rf, x, cm, sm, emit);
    } break;
    case 2: {
        float pmm = 3.0f * sx2, rfm = rf2, cm = c2, sm = s2;
        chain<2>(t, row, pmm, rfm, rf, x, cm, sm, emit);
        pmm *= -45045.0f * sx5; rfm *= rf5; ROT(cm, sm, c5, s5);    // 5*7*9*11*13
        chain<7>(t, row, pmm, rfm, rf, x, cm, sm, emit);
        pmm *= -15.0f * somx2;  rfm *= rf;  ROT(cm, sm, c1, s1);    // 15
        chain<8>(t, row, pmm, rfm, rf, x, cm, sm, emit);
    } break;
    default: {
        float pmm = -15.0f * sx3, rfm = rf3, cm = c3, sm = s3;
        chain<3>(t, row, pmm, rfm, rf, x, cm, sm, emit);
        pmm *= -7.0f * somx2; rfm *= rf; ROT(cm, sm, c1, s1);       // 7
        chain<4>(t, row, pmm, rfm, rf, x, cm, sm, emit);
    } break;
    }
#undef ROT
}

struct EmitH {
    __device__ void operator()(__half* row, int j, float v) const {
        row[j] = __float2half(v);
    }
};
struct EmitF {
    __device__ void operator()(float* row, int j, float v) const {
        row[j] = v;
    }
};

// ---- stream one fp16 tile to global as f32, NT float4 stores ----
__device__ __forceinline__ void store_tile(const __half* __restrict__ buf,
                                           f4_t* __restrict__ dst) {
    const uint2* __restrict__ src = (const uint2*)buf;   // 4 halves per chunk
#pragma unroll
    for (int k = 0; k < 7; ++k) {
        int i = threadIdx.x + k * 256;
        uint2 h = src[i];
        float2 fa = __half22float2(*(const __half2*)&h.x);
        float2 fb = __half22float2(*(const __half2*)&h.y);
        f4_t v = {fa.x, fa.y, fb.x, fb.y};
        __builtin_nontemporal_store(v, &dst[i]);
    }
    if (threadIdx.x < TILE4 - 7 * 256) {     // 1936 - 1792 = 144
        int i = threadIdx.x + 7 * 256;
        uint2 h = src[i];
        float2 fa = __half22float2(*(const __half2*)&h.x);
        float2 fb = __half22float2(*(const __half2*)&h.y);
        f4_t v = {fa.x, fa.y, fb.x, fb.y};
        __builtin_nontemporal_store(v, &dst[i]);
    }
}

// ---- persistent pipelined kernel: store(prev) overlaps compute(cur) ----
__global__ __launch_bounds__(256, 5)
void sh_main(const float* __restrict__ in, float* __restrict__ out,
             int ntiles, Tab t) {
    __shared__ __half lds[2][TILEH];

    const int p = threadIdx.x & 63;
    const int s = threadIdx.x >> 6;          // wave-uniform m-group

    int tile = blockIdx.x;
    if (tile >= ntiles) return;

    compute_tile(in, (long long)tile * PPB + p, s, t, &lds[0][p * NCOL], EmitH{});
    __syncthreads();

    int buf = 0;
    int prev = tile;
    for (tile += gridDim.x; tile < ntiles; tile += gridDim.x) {
        // issue prev tile's stores first (fire-and-forget), then compute next
        store_tile(lds[buf], (f4_t*)out + (long long)prev * TILE4);
        compute_tile(in, (long long)tile * PPB + p, s, t, &lds[buf ^ 1][p * NCOL], EmitH{});
        __syncthreads();
        buf ^= 1;
        prev = tile;
    }
    store_tile(lds[buf], (f4_t*)out + (long long)prev * TILE4);
}

// ---- guarded tail kernel (n % 64 != 0), f32 path ----
__global__ __launch_bounds__(256)
void sh_tail(const float* __restrict__ in, float* __restrict__ out,
             int n, int tile0, Tab t) {
    __shared__ float lds[PPB * NCOL];
    const int p = threadIdx.x & 63;
    const int s = threadIdx.x >> 6;
    const long long gp = (long long)tile0 * PPB + p;
    if (gp < n)
        compute_tile(in, gp, s, t, &lds[p * NCOL], EmitF{});
    __syncthreads();
    const long long lim4 = ((long long)n * NCOL + 3) / 4;
    const long long base4 = (long long)tile0 * TILE4;
    f4_t* dst = (f4_t*)out + base4;
    const f4_t* src = (const f4_t*)lds;
    for (int f = threadIdx.x; f < TILE4; f += 256)
        if (base4 + f < lim4)
            __builtin_nontemporal_store(src[f], &dst[f]);
}

extern "C" void kernel_launch(void* const* d_in, const int* in_sizes, int n_in,
                              void* d_out, int out_size, void* d_ws, size_t ws_size,
                              hipStream_t stream) {
    const float* in = (const float*)d_in[0];
    float* out = (float*)d_out;
    const int n = in_sizes[0] / 3;

    Tab t;
    double fact[2 * LMAX + 1];
    fact[0] = 1.0;
    for (int i = 1; i <= 2 * LMAX; ++i) fact[i] = fact[i - 1] * (double)i;
    for (int l = 0; l <= LMAX; ++l) {
        for (int m = 0; m <= l; ++m) {
            int ti = l * (l + 1) / 2 + m;
            double k = sqrt((2.0 * l + 1.0) * fact[l - m] / fact[l + m]);
            if (m > 0) k *= sqrt(2.0);
            t.K[ti] = (float)k;
            if (l >= m + 2) {
                t.A[ti] = (float)((2.0 * l - 1.0) / (double)(l - m));
                t.B[ti] = (float)(((double)(l + m) - 1.0) / (double)(l - m));
            } else {
                t.A[ti] = 0.0f; t.B[ti] = 0.0f;
            }
        }
    }

    const int full_tiles = n / PPB;
    if (full_tiles > 0) {
        int nblk = full_tiles < 1280 ? full_tiles : 1280;   // 5 blocks/CU x 256 CU
        sh_main<<<nblk, 256, 0, stream>>>(in, out, full_tiles, t);
    }
    if (n - full_tiles * PPB > 0)
        sh_tail<<<1, 256, 0, stream>>>(in, out, n, full_tiles, t);
}

// Round 6
// 97.655 us; speedup vs baseline: 1.0547x; 1.0547x over previous
//
#include <hip/hip_runtime.h>
#include <hip/hip_fp16.h>
#include <math.h>

#define LMAX 10
#define NCOL 121                 // (LMAX+1)^2
#define PPB  64                  // points per tile
#define TILEH (PPB * NCOL)       // 7744 halves per tile buffer (15.5 KB)
#define TILE4 (PPB * NCOL / 4)   // 1936 output float4 per tile

typedef float f4_t __attribute__((ext_vector_type(4)));

struct Tab {
    float K[66];   // K(l,m) (* sqrt2 for m>0), index l(l+1)/2+m
    float A[66];   // (2l-1)/(l-m)    for l>=m+2
    float B[66];   // (l+m-1)/(l-m)   for l>=m+2
};

// ---- chain for fixed M: emit K*P(l,M)*rf^l * {cos,sin}(M phi), l=M..LMAX ----
template<int M, typename ST, typename EMIT>
__device__ __forceinline__ void chain(const Tab& t, ST* __restrict__ row,
                                      float pmm, float rfm, float rf, float x,
                                      float cm, float sm, EMIT emit) {
    {
        float v = t.K[M * (M + 1) / 2 + M] * pmm * rfm;
        if constexpr (M == 0) emit(row, 0, v);
        else { emit(row, M * M + 2 * M, v * cm); emit(row, M * M, v * sm); }
    }
    if constexpr (M < LMAX) {
        float p0 = pmm;
        float p1 = x * (float)(2 * M + 1) * pmm;
        float rfl = rfm * rf;
        {
            constexpr int L = M + 1;
            float v = t.K[L * (L + 1) / 2 + M] * p1 * rfl;
            if constexpr (M == 0) emit(row, L * L + L, v);
            else { emit(row, L * L + L + M, v * cm); emit(row, L * L + L - M, v * sm); }
        }
#pragma unroll
        for (int ll = M + 2; ll <= LMAX; ++ll) {
            int ti = ll * (ll + 1) / 2 + M;
            float p2 = t.A[ti] * x * p1 - t.B[ti] * p0;
            p0 = p1; p1 = p2;
            rfl *= rf;
            float v = t.K[ti] * p1 * rfl;
            int jb = ll * ll + ll;
            if constexpr (M == 0) emit(row, jb, v);
            else { emit(row, jb + M, v * cm); emit(row, jb - M, v * sm); }
        }
    }
}

// ---- compute one point's contribution (m-set s) into its LDS row ----
template<typename ST, typename EMIT>
__device__ __forceinline__ void compute_tile(const float* __restrict__ in,
                                             long long gp, int s, const Tab& t,
                                             ST* __restrict__ row, EMIT emit) {
    const float lon = in[gp * 3 + 0];
    const float lat = in[gp * 3 + 1];
    const float r   = in[gp * 3 + 2];

    const float D2R  = 0.017453292519943295f;
    const float PI_F = 3.14159265358979323846f;

    float phi   = (lon + 180.0f) * D2R;
    float theta = fminf(fmaxf((90.0f - lat) * D2R, 1e-7f), PI_F - 1e-7f);
    float x = __cosf(theta);
    x = fminf(fmaxf(x, -1.0f + 1e-7f), 1.0f - 1e-7f);
    float somx2 = sqrtf(fmaxf((1.0f - x) * (1.0f + x), 0.0f));
    float rf  = 6371000.0f / r;
    float rf2 = rf * rf;
    float rf3 = rf2 * rf;
    float rf5 = rf3 * rf2;

    float c1, s1;
    __sincosf(phi, &s1, &c1);
    float c2 = c1 * c1 - s1 * s1, s2 = 2.0f * c1 * s1;
    float c3 = c2 * c1 - s2 * s1, s3 = s2 * c1 + c2 * s1;
    float c5 = (c2 * c2 - s2 * s2) * c1 - 2.0f * c2 * s2 * s1;
    float s5 = 2.0f * c2 * s2 * c1 + (c2 * c2 - s2 * s2) * s1;

    float sx2 = somx2 * somx2;
    float sx3 = sx2 * somx2;
    float sx5 = sx3 * sx2;

#define ROT(cm, sm, ck, sk) { float cn = cm * ck - sm * sk; sm = sm * ck + cm * sk; cm = cn; }
    // m-sets balanced by chain length: {0,5,10}, {1,6,9}, {2,7,8}, {3,4}
    switch (s) {
    case 0: {
        float pmm = 1.0f, rfm = 1.0f, cm = 1.0f, sm = 0.0f;
        chain<0>(t, row, pmm, rfm, rf, x, cm, sm, emit);
        pmm *= -945.0f    * sx5; rfm *= rf5; ROT(cm, sm, c5, s5);   // 1*3*5*7*9
        chain<5>(t, row, pmm, rfm, rf, x, cm, sm, emit);
        pmm *= -692835.0f * sx5; rfm *= rf5; ROT(cm, sm, c5, s5);   // 11*13*15*17*19
        chain<10>(t, row, pmm, rfm, rf, x, cm, sm, emit);
    } break;
    case 1: {
        float pmm = -somx2, rfm = rf, cm = c1, sm = s1;
        chain<1>(t, row, pmm, rfm, rf, x, cm, sm, emit);
        pmm *= -10395.0f * sx5; rfm *= rf5; ROT(cm, sm, c5, s5);    // 3*5*7*9*11
        chain<6>(t, row, pmm, rfm, rf, x, cm, sm, emit);
        pmm *= -3315.0f  * sx3; rfm *= rf3; ROT(cm, sm, c3, s3);    // 13*15*17
        chain<9>(t, row, pmm, rfm, rf, x, cm, sm, emit);
    } break;
    case 2: {
        float pmm = 3.0f * sx2, rfm = rf2, cm = c2, sm = s2;
        chain<2>(t, row, pmm, rfm, rf, x, cm, sm, emit);
        pmm *= -45045.0f * sx5; rfm *= rf5; ROT(cm, sm, c5, s5);    // 5*7*9*11*13
        chain<7>(t, row, pmm, rfm, rf, x, cm, sm, emit);
        pmm *= -15.0f * somx2;  rfm *= rf;  ROT(cm, sm, c1, s1);    // 15
        chain<8>(t, row, pmm, rfm, rf, x, cm, sm, emit);
    } break;
    default: {
        float pmm = -15.0f * sx3, rfm = rf3, cm = c3, sm = s3;
        chain<3>(t, row, pmm, rfm, rf, x, cm, sm, emit);
        pmm *= -7.0f * somx2; rfm *= rf; ROT(cm, sm, c1, s1);       // 7
        chain<4>(t, row, pmm, rfm, rf, x, cm, sm, emit);
    } break;
    }
#undef ROT
}

struct EmitH {
    __device__ void operator()(__half* row, int j, float v) const {
        row[j] = __float2half(v);
    }
};
struct EmitF {
    __device__ void operator()(float* row, int j, float v) const {
        row[j] = v;
    }
};

// ---- one-shot kernel, fp16 tile (15.5 KB) -> 8 blocks/CU, NT f32 stores ----
__global__ __launch_bounds__(256, 8)
void sh_main(const float* __restrict__ in, float* __restrict__ out, Tab t) {
    __shared__ __half lds[TILEH];              // [point][j], fp16, == out order

    const int p = threadIdx.x & 63;
    const int s = threadIdx.x >> 6;            // wave-uniform m-group

    compute_tile(in, (long long)blockIdx.x * PPB + p, s, t,
                 &lds[p * NCOL], EmitH{});
    __syncthreads();

    // Epilogue: linear copy, convert fp16 -> f32, NT float4 stores
    f4_t* __restrict__ dst = (f4_t*)out + (long long)blockIdx.x * TILE4;
    const uint2* __restrict__ src = (const uint2*)lds;   // 4 halves per chunk
#pragma unroll
    for (int k = 0; k < 7; ++k) {
        int i = threadIdx.x + k * 256;
        uint2 h = src[i];
        float2 fa = __half22float2(*(const __half2*)&h.x);
        float2 fb = __half22float2(*(const __half2*)&h.y);
        f4_t v = {fa.x, fa.y, fb.x, fb.y};
        __builtin_nontemporal_store(v, &dst[i]);
    }
    if (threadIdx.x < TILE4 - 7 * 256) {       // 1936 - 1792 = 144
        int i = threadIdx.x + 7 * 256;
        uint2 h = src[i];
        float2 fa = __half22float2(*(const __half2*)&h.x);
        float2 fb = __half22float2(*(const __half2*)&h.y);
        f4_t v = {fa.x, fa.y, fb.x, fb.y};
        __builtin_nontemporal_store(v, &dst[i]);
    }
}

// ---- guarded tail kernel (n % 64 != 0), f32 path ----
__global__ __launch_bounds__(256)
void sh_tail(const float* __restrict__ in, float* __restrict__ out,
             int n, int tile0, Tab t) {
    __shared__ float lds[PPB * NCOL];
    const int p = threadIdx.x & 63;
    const int s = threadIdx.x >> 6;
    const long long gp = (long long)tile0 * PPB + p;
    if (gp < n)
        compute_tile(in, gp, s, t, &lds[p * NCOL], EmitF{});
    __syncthreads();
    const long long lim4 = ((long long)n * NCOL + 3) / 4;
    const long long base4 = (long long)tile0 * TILE4;
    f4_t* dst = (f4_t*)out + base4;
    const f4_t* src = (const f4_t*)lds;
    for (int f = threadIdx.x; f < TILE4; f += 256)
        if (base4 + f < lim4)
            __builtin_nontemporal_store(src[f], &dst[f]);
}

extern "C" void kernel_launch(void* const* d_in, const int* in_sizes, int n_in,
                              void* d_out, int out_size, void* d_ws, size_t ws_size,
                              hipStream_t stream) {
    const float* in = (const float*)d_in[0];
    float* out = (float*)d_out;
    const int n = in_sizes[0] / 3;

    Tab t;
    double fact[2 * LMAX + 1];
    fact[0] = 1.0;
    for (int i = 1; i <= 2 * LMAX; ++i) fact[i] = fact[i - 1] * (double)i;
    for (int l = 0; l <= LMAX; ++l) {
        for (int m = 0; m <= l; ++m) {
            int ti = l * (l + 1) / 2 + m;
            double k = sqrt((2.0 * l + 1.0) * fact[l - m] / fact[l + m]);
            if (m > 0) k *= sqrt(2.0);
            t.K[ti] = (float)k;
            if (l >= m + 2) {
                t.A[ti] = (float)((2.0 * l - 1.0) / (double)(l - m));
                t.B[ti] = (float)(((double)(l + m) - 1.0) / (double)(l - m));
            } else {
                t.A[ti] = 0.0f; t.B[ti] = 0.0f;
            }
        }
    }

    const int full_tiles = n / PPB;
    if (full_tiles > 0)
        sh_main<<<full_tiles, 256, 0, stream>>>(in, out, t);
    if (n - full_tiles * PPB > 0)
        sh_tail<<<1, 256, 0, stream>>>(in, out, n, full_tiles, t);
}

// Round 7
// 93.146 us; speedup vs baseline: 1.1058x; 1.0484x over previous
//
#include <hip/hip_runtime.h>
#include <hip/hip_fp16.h>
#include <math.h>

#define LMAX 10
#define NCOL 121                 // (LMAX+1)^2
#define PPB  64                  // points per wave-tile
#define WPB  4                   // wave-tiles per 256-thread block
#define TILEH (PPB * NCOL)       // 7744 halves per tile (15.5 KB)
#define TILE4 (PPB * NCOL / 4)   // 1936 output float4 per tile

typedef float f4_t __attribute__((ext_vector_type(4)));

struct Tab {
    float K[66];   // K(l,m) (* sqrt2 for m>0), index l(l+1)/2+m
    float A[66];   // (2l-1)/(l-m)    for l>=m+2
    float B[66];   // (l+m-1)/(l-m)   for l>=m+2
};

// ---- chain for fixed M: emit K*P(l,M)*rf^l * {cos,sin}(M phi), l=M..LMAX ----
template<int M, typename ST, typename EMIT>
__device__ __forceinline__ void chain(const Tab& t, ST* __restrict__ row,
                                      float pmm, float rfm, float rf, float x,
                                      float cm, float sm, EMIT emit) {
    {
        float v = t.K[M * (M + 1) / 2 + M] * pmm * rfm;
        if constexpr (M == 0) emit(row, 0, v);
        else { emit(row, M * M + 2 * M, v * cm); emit(row, M * M, v * sm); }
    }
    if constexpr (M < LMAX) {
        float p0 = pmm;
        float p1 = x * (float)(2 * M + 1) * pmm;
        float rfl = rfm * rf;
        {
            constexpr int L = M + 1;
            float v = t.K[L * (L + 1) / 2 + M] * p1 * rfl;
            if constexpr (M == 0) emit(row, L * L + L, v);
            else { emit(row, L * L + L + M, v * cm); emit(row, L * L + L - M, v * sm); }
        }
#pragma unroll
        for (int ll = M + 2; ll <= LMAX; ++ll) {
            int ti = ll * (ll + 1) / 2 + M;
            float p2 = t.A[ti] * x * p1 - t.B[ti] * p0;
            p0 = p1; p1 = p2;
            rfl *= rf;
            float v = t.K[ti] * p1 * rfl;
            int jb = ll * ll + ll;
            if constexpr (M == 0) emit(row, jb, v);
            else { emit(row, jb + M, v * cm); emit(row, jb - M, v * sm); }
        }
    }
}

#define ROT(cm, sm, ck, sk) { float cn = cm * ck - sm * sk; sm = sm * ck + cm * sk; cm = cn; }

// ---- per-point setup shared by both kernels ----
struct Setup {
    float x, somx2, rf, rf2, rf3, rf5;
    float c1, s1, c2, s2, c3, s3, c5, s5;
    float sx2, sx3, sx5;
};

__device__ __forceinline__ Setup sh_setup(const float* __restrict__ in, long long gp) {
    Setup u;
    const float lon = in[gp * 3 + 0];
    const float lat = in[gp * 3 + 1];
    const float r   = in[gp * 3 + 2];

    const float D2R  = 0.017453292519943295f;
    const float PI_F = 3.14159265358979323846f;

    float phi   = (lon + 180.0f) * D2R;
    float theta = fminf(fmaxf((90.0f - lat) * D2R, 1e-7f), PI_F - 1e-7f);
    float x = __cosf(theta);
    x = fminf(fmaxf(x, -1.0f + 1e-7f), 1.0f - 1e-7f);
    u.x = x;
    u.somx2 = sqrtf(fmaxf((1.0f - x) * (1.0f + x), 0.0f));
    u.rf  = 6371000.0f / r;
    u.rf2 = u.rf * u.rf;
    u.rf3 = u.rf2 * u.rf;
    u.rf5 = u.rf3 * u.rf2;

    __sincosf(phi, &u.s1, &u.c1);
    u.c2 = u.c1 * u.c1 - u.s1 * u.s1;  u.s2 = 2.0f * u.c1 * u.s1;
    u.c3 = u.c2 * u.c1 - u.s2 * u.s1;  u.s3 = u.s2 * u.c1 + u.c2 * u.s1;
    float c4 = u.c2 * u.c2 - u.s2 * u.s2, s4 = 2.0f * u.c2 * u.s2;
    u.c5 = c4 * u.c1 - s4 * u.s1;      u.s5 = s4 * u.c1 + c4 * u.s1;

    u.sx2 = u.somx2 * u.somx2;
    u.sx3 = u.sx2 * u.somx2;
    u.sx5 = u.sx3 * u.sx2;
    return u;
}

// ---- one m-set (for the tail kernel's 4-way split) ----
template<typename ST, typename EMIT>
__device__ __forceinline__ void compute_mset(const Setup& u, int s, const Tab& t,
                                             ST* __restrict__ row, EMIT emit) {
    switch (s) {
    case 0: {
        float pmm = 1.0f, rfm = 1.0f, cm = 1.0f, sm = 0.0f;
        chain<0>(t, row, pmm, rfm, u.rf, u.x, cm, sm, emit);
        pmm *= -945.0f    * u.sx5; rfm *= u.rf5; ROT(cm, sm, u.c5, u.s5);
        chain<5>(t, row, pmm, rfm, u.rf, u.x, cm, sm, emit);
        pmm *= -692835.0f * u.sx5; rfm *= u.rf5; ROT(cm, sm, u.c5, u.s5);
        chain<10>(t, row, pmm, rfm, u.rf, u.x, cm, sm, emit);
    } break;
    case 1: {
        float pmm = -u.somx2, rfm = u.rf, cm = u.c1, sm = u.s1;
        chain<1>(t, row, pmm, rfm, u.rf, u.x, cm, sm, emit);
        pmm *= -10395.0f * u.sx5; rfm *= u.rf5; ROT(cm, sm, u.c5, u.s5);
        chain<6>(t, row, pmm, rfm, u.rf, u.x, cm, sm, emit);
        pmm *= -3315.0f  * u.sx3; rfm *= u.rf3; ROT(cm, sm, u.c3, u.s3);
        chain<9>(t, row, pmm, rfm, u.rf, u.x, cm, sm, emit);
    } break;
    case 2: {
        float pmm = 3.0f * u.sx2, rfm = u.rf2, cm = u.c2, sm = u.s2;
        chain<2>(t, row, pmm, rfm, u.rf, u.x, cm, sm, emit);
        pmm *= -45045.0f * u.sx5; rfm *= u.rf5; ROT(cm, sm, u.c5, u.s5);
        chain<7>(t, row, pmm, rfm, u.rf, u.x, cm, sm, emit);
        pmm *= -15.0f * u.somx2;  rfm *= u.rf;  ROT(cm, sm, u.c1, u.s1);
        chain<8>(t, row, pmm, rfm, u.rf, u.x, cm, sm, emit);
    } break;
    default: {
        float pmm = -15.0f * u.sx3, rfm = u.rf3, cm = u.c3, sm = u.s3;
        chain<3>(t, row, pmm, rfm, u.rf, u.x, cm, sm, emit);
        pmm *= -7.0f * u.somx2; rfm *= u.rf; ROT(cm, sm, u.c1, u.s1);
        chain<4>(t, row, pmm, rfm, u.rf, u.x, cm, sm, emit);
    } break;
    }
}

// ---- full 121-coefficient compute for one point (main kernel, no m-split) ----
template<typename ST, typename EMIT>
__device__ __forceinline__ void compute_point_all(const Setup& u, const Tab& t,
                                                  ST* __restrict__ row, EMIT emit) {
    compute_mset(u, 0, t, row, emit);
    compute_mset(u, 1, t, row, emit);
    compute_mset(u, 2, t, row, emit);
    compute_mset(u, 3, t, row, emit);
}

struct EmitH {
    __device__ void operator()(__half* row, int j, float v) const {
        row[j] = __float2half(v);
    }
};
struct EmitF {
    __device__ void operator()(float* row, int j, float v) const {
        row[j] = v;
    }
};

// ---- barrier-free main kernel: one tile per WAVE, fp16 staging ----
__global__ __launch_bounds__(256)
void sh_main(const float* __restrict__ in, float* __restrict__ out,
             int ntiles, Tab t) {
    __shared__ __half lds[WPB][TILEH];          // 4 x 15.5 KB = 62 KB

    const int w    = threadIdx.x >> 6;          // wave id
    const int lane = threadIdx.x & 63;
    const int wtile = blockIdx.x * WPB + w;
    if (wtile >= ntiles) return;                // no barriers anywhere: safe

    __half* row = &lds[w][lane * NCOL];
    Setup u = sh_setup(in, (long long)wtile * PPB + lane);
    compute_point_all(u, t, row, EmitH{});

    // wave-local fence: all this wave's ds_writes complete; no __syncthreads
    asm volatile("s_waitcnt lgkmcnt(0)" ::: "memory");

    // stream this wave's private tile out, fp16 -> f32, NT float4 stores
    const uint2* __restrict__ src = (const uint2*)&lds[w][0];   // 4 halves each
    f4_t* __restrict__ dst = (f4_t*)out + (long long)wtile * TILE4;
#pragma unroll
    for (int k = 0; k < 30; ++k) {              // 30*64 = 1920 of 1936
        int i = lane + k * 64;
        uint2 h = src[i];
        float2 fa = __half22float2(*(const __half2*)&h.x);
        float2 fb = __half22float2(*(const __half2*)&h.y);
        f4_t v = {fa.x, fa.y, fb.x, fb.y};
        __builtin_nontemporal_store(v, &dst[i]);
    }
    if (lane < 16) {                            // remaining 16 chunks
        int i = lane + 30 * 64;
        uint2 h = src[i];
        float2 fa = __half22float2(*(const __half2*)&h.x);
        float2 fb = __half22float2(*(const __half2*)&h.y);
        f4_t v = {fa.x, fa.y, fb.x, fb.y};
        __builtin_nontemporal_store(v, &dst[i]);
    }
}

// ---- guarded tail kernel (n % 64 != 0), f32, block-level (unused at n=1e6) ----
__global__ __launch_bounds__(256)
void sh_tail(const float* __restrict__ in, float* __restrict__ out,
             int n, int tile0, Tab t) {
    __shared__ float lds[PPB * NCOL];
    const int p = threadIdx.x & 63;
    const int s = threadIdx.x >> 6;
    const long long gp = (long long)tile0 * PPB + p;
    if (gp < n) {
        Setup u = sh_setup(in, gp);
        compute_mset(u, s, t, &lds[p * NCOL], EmitF{});
    }
    __syncthreads();
    const long long lim4 = ((long long)n * NCOL + 3) / 4;
    const long long base4 = (long long)tile0 * TILE4;
    f4_t* dst = (f4_t*)out + base4;
    const f4_t* src = (const f4_t*)lds;
    for (int f = threadIdx.x; f < TILE4; f += 256)
        if (base4 + f < lim4)
            __builtin_nontemporal_store(src[f], &dst[f]);
}

extern "C" void kernel_launch(void* const* d_in, const int* in_sizes, int n_in,
                              void* d_out, int out_size, void* d_ws, size_t ws_size,
                              hipStream_t stream) {
    const float* in = (const float*)d_in[0];
    float* out = (float*)d_out;
    const int n = in_sizes[0] / 3;

    Tab t;
    double fact[2 * LMAX + 1];
    fact[0] = 1.0;
    for (int i = 1; i <= 2 * LMAX; ++i) fact[i] = fact[i - 1] * (double)i;
    for (int l = 0; l <= LMAX; ++l) {
        for (int m = 0; m <= l; ++m) {
            int ti = l * (l + 1) / 2 + m;
            double k = sqrt((2.0 * l + 1.0) * fact[l - m] / fact[l + m]);
            if (m > 0) k *= sqrt(2.0);
            t.K[ti] = (float)k;
            if (l >= m + 2) {
                t.A[ti] = (float)((2.0 * l - 1.0) / (double)(l - m));
                t.B[ti] = (float)(((double)(l + m) - 1.0) / (double)(l - m));
            } else {
                t.A[ti] = 0.0f; t.B[ti] = 0.0f;
            }
        }
    }

    const int full_tiles = n / PPB;
    if (full_tiles > 0) {
        const int blocks = (full_tiles + WPB - 1) / WPB;
        sh_main<<<blocks, 256, 0, stream>>>(in, out, full_tiles, t);
    }
    if (n - full_tiles * PPB > 0)
        sh_tail<<<1, 256, 0, stream>>>(in, out, n, full_tiles, t);
}